// Round 3
// baseline (391.939 us; speedup 1.0000x reference)
//
#include <hip/hip_runtime.h>

// Distances: out[b,o] = sqrt(max(|x_b|^2 - 2*x.wcol_o + |w_o|^2, 0))
// x: [8192][4096] fp32, weight: [1][4096][2048] fp32, out: [8192][2048] fp32.
// Strategy: fp32 norms + bf16 MFMA GEMM (m97 128^2 structure, global_load_lds,
// source-side XOR swizzle, XCD-aware block swizzle), fused sqrt epilogue.
// Fallback fp32 path if workspace too small.

static constexpr int Mdim = 8192;
static constexpr int Ndim = 2048;
static constexpr int Kdim = 4096;

#define TILE_M 128
#define TILE_N 128
#define TILE_K 32

typedef float f32x4 __attribute__((ext_vector_type(4)));
typedef short s16x8 __attribute__((ext_vector_type(8)));
typedef __attribute__((address_space(3))) unsigned int lds_u32;
typedef const __attribute__((address_space(1))) unsigned int glb_u32;

__device__ __forceinline__ unsigned short f2bf(float f) {
    unsigned int u = __float_as_uint(f);
    return (unsigned short)((u + 0x7fffu + ((u >> 16) & 1u)) >> 16);  // RNE
}

// ---------------- prep: x -> bf16, x2 row norms ----------------
__global__ void prep_x_kernel(const float* __restrict__ x,
                              unsigned short* __restrict__ xb,
                              float* __restrict__ x2) {
    const int row = blockIdx.x;
    const int tid = threadIdx.x;
    const float4* xr = (const float4*)(x + (size_t)row * Kdim);
    ushort4* xo = (ushort4*)(xb + (size_t)row * Kdim);
    float ss = 0.f;
#pragma unroll
    for (int j = 0; j < 4; ++j) {
        float4 v = xr[j * 256 + tid];
        ss += v.x * v.x + v.y * v.y + v.z * v.z + v.w * v.w;
        ushort4 o;
        o.x = f2bf(v.x); o.y = f2bf(v.y); o.z = f2bf(v.z); o.w = f2bf(v.w);
        xo[j * 256 + tid] = o;
    }
#pragma unroll
    for (int d = 32; d >= 1; d >>= 1) ss += __shfl_down(ss, d, 64);
    __shared__ float ps[4];
    if ((tid & 63) == 0) ps[tid >> 6] = ss;
    __syncthreads();
    if (tid == 0) x2[row] = ps[0] + ps[1] + ps[2] + ps[3];
}

// ------- prep: w [K][N] -> wT bf16 [N][K], fused w2 column norms -------
__global__ void prep_wt_kernel(const float* __restrict__ w,
                               unsigned short* __restrict__ wb,
                               float* __restrict__ w2) {
    __shared__ float t[64][65];  // +1 pad: 2-way banks only (free)
    const int tid = threadIdx.x;
    const int c0 = blockIdx.x * 64;  // N
    const int r0 = blockIdx.y * 64;  // K
#pragma unroll
    for (int p = 0; p < 4; ++p) {
        const int r = p * 16 + (tid >> 4);
        const int c = (tid & 15) * 4;
        float4 v = *(const float4*)(w + (size_t)(r0 + r) * Ndim + c0 + c);
        t[r][c] = v.x; t[r][c + 1] = v.y; t[r][c + 2] = v.z; t[r][c + 3] = v.w;
    }
    __syncthreads();
#pragma unroll
    for (int p = 0; p < 2; ++p) {
        const int o  = p * 32 + (tid >> 3);   // output row (w column)
        const int kc = (tid & 7) * 8;         // k chunk
        float ss = 0.f;
        ushort4 a, b;
        float v;
        v = t[kc + 0][o]; ss += v * v; a.x = f2bf(v);
        v = t[kc + 1][o]; ss += v * v; a.y = f2bf(v);
        v = t[kc + 2][o]; ss += v * v; a.z = f2bf(v);
        v = t[kc + 3][o]; ss += v * v; a.w = f2bf(v);
        v = t[kc + 4][o]; ss += v * v; b.x = f2bf(v);
        v = t[kc + 5][o]; ss += v * v; b.y = f2bf(v);
        v = t[kc + 6][o]; ss += v * v; b.z = f2bf(v);
        v = t[kc + 7][o]; ss += v * v; b.w = f2bf(v);
        ushort4* dst = (ushort4*)(wb + (size_t)(c0 + o) * Kdim + r0 + kc);
        dst[0] = a; dst[1] = b;
        // 8-lane (same o) shuffle reduce, one atomic per column per block
        ss += __shfl_xor(ss, 1, 64);
        ss += __shfl_xor(ss, 2, 64);
        ss += __shfl_xor(ss, 4, 64);
        if ((tid & 7) == 0) atomicAdd(&w2[c0 + o], ss);
    }
}

// ---------------- main GEMM + fused distance epilogue ----------------
// 128x128 tile, BK=32, 4 waves (2x2), each wave 64x64 = 4x4 frags of 16x16x32.
// LDS double-buffered; staged via global_load_lds width=16 with linear LDS dest +
// chunk-permuted global source; fragment reads apply the same XOR (rule #21).
// 1D grid + bijective XCD swizzle (nwg=1024, %8==0).
__global__ __launch_bounds__(256, 2) void gemm_dist_kernel(
    const unsigned short* __restrict__ Xb,   // [M][K] bf16
    const unsigned short* __restrict__ Wb,   // [N][K] bf16
    const float* __restrict__ x2,            // [M]
    const float* __restrict__ w2,            // [N]
    float* __restrict__ out)                 // [M][N]
{
    __shared__ __align__(16) unsigned char lds[2][16384];  // per buf: A[128][32] | B[128][32] bf16
    const int tid = threadIdx.x;
    const int lane = tid & 63;
    const int wid = tid >> 6;
    const int wr = wid >> 1, wc = wid & 1;

    // XCD-aware bijective swizzle: nwg = 1024, q = 128
    const int nt_n = Ndim / TILE_N;              // 16
    const int nwg = (Mdim / TILE_M) * nt_n;      // 1024
    const int q = nwg >> 3;
    const int swz = (blockIdx.x & 7) * q + (blockIdx.x >> 3);
    const int bm0 = (swz / nt_n) * TILE_M;
    const int bn0 = (swz % nt_n) * TILE_N;

    // staging: 512 16B chunks per operand tile; chunk c -> LDS byte c*16 holds
    // row=c>>2, k-chunk (c^row)&3 (source-side swizzle).
    int srcA[2], srcB[2];
#pragma unroll
    for (int j = 0; j < 2; ++j) {
        int chunk = j * 256 + tid;
        int row = chunk >> 2;
        int scir = (chunk ^ row) & 3;
        srcA[j] = (bm0 + row) * Kdim + scir * 8;  // element offset (8 bf16 = 16B)
        srcB[j] = (bn0 + row) * Kdim + scir * 8;
    }

    // fragment read offsets (bytes), same XOR as source perm
    int aoff[4], boff[4];
#pragma unroll
    for (int m = 0; m < 4; ++m) {
        int ra = wr * 64 + m * 16 + (lane & 15);
        aoff[m] = ra * 64 + ((((lane >> 4) ^ ra) & 3) << 4);
        int rb = wc * 64 + m * 16 + (lane & 15);
        boff[m] = 8192 + rb * 64 + ((((lane >> 4) ^ rb) & 3) << 4);
    }

    f32x4 acc[4][4];
#pragma unroll
    for (int m = 0; m < 4; ++m)
#pragma unroll
        for (int n = 0; n < 4; ++n) acc[m][n] = (f32x4){0.f, 0.f, 0.f, 0.f};

    auto stage = [&](int bufi, int kt) {
        const unsigned short* ga0 = Xb + srcA[0] + kt * TILE_K;
        const unsigned short* ga1 = Xb + srcA[1] + kt * TILE_K;
        const unsigned short* gb0 = Wb + srcB[0] + kt * TILE_K;
        const unsigned short* gb1 = Wb + srcB[1] + kt * TILE_K;
        unsigned char* base = &lds[bufi][0];
        // LDS dest = wave-uniform base + lane*16 (HW-added)
        __builtin_amdgcn_global_load_lds((glb_u32*)ga0, (lds_u32*)(base + wid * 1024), 16, 0, 0);
        __builtin_amdgcn_global_load_lds((glb_u32*)ga1, (lds_u32*)(base + 4096 + wid * 1024), 16, 0, 0);
        __builtin_amdgcn_global_load_lds((glb_u32*)gb0, (lds_u32*)(base + 8192 + wid * 1024), 16, 0, 0);
        __builtin_amdgcn_global_load_lds((glb_u32*)gb1, (lds_u32*)(base + 8192 + 4096 + wid * 1024), 16, 0, 0);
    };

    stage(0, 0);
    __syncthreads();  // drains vmcnt(0)

    const int NT = Kdim / TILE_K;
    for (int kt = 0; kt < NT; ++kt) {
        const int cur = kt & 1;
        if (kt + 1 < NT) stage(cur ^ 1, kt + 1);
        const unsigned char* buf = &lds[cur][0];
        s16x8 af[4], bf[4];
#pragma unroll
        for (int m = 0; m < 4; ++m) af[m] = *(const s16x8*)(buf + aoff[m]);
#pragma unroll
        for (int n = 0; n < 4; ++n) bf[n] = *(const s16x8*)(buf + boff[n]);
#pragma unroll
        for (int m = 0; m < 4; ++m)
#pragma unroll
            for (int n = 0; n < 4; ++n)
                acc[m][n] = __builtin_amdgcn_mfma_f32_16x16x32_bf16(af[m], bf[n], acc[m][n], 0, 0, 0);
        __syncthreads();  // next buffer staged (vmcnt), this buffer's reads done (lgkmcnt)
    }

    // epilogue: D mapping col=lane&15, row=(lane>>4)*4+reg [m89/m91-verified]
    const int col0 = bn0 + wc * 64 + (lane & 15);
    const int rb0 = bm0 + wr * 64 + ((lane >> 4) << 2);
    float w2v[4];
#pragma unroll
    for (int n = 0; n < 4; ++n) w2v[n] = w2[col0 + n * 16];
#pragma unroll
    for (int m = 0; m < 4; ++m) {
#pragma unroll
        for (int i = 0; i < 4; ++i) {
            const int row = rb0 + m * 16 + i;
            const float xv = x2[row];
#pragma unroll
            for (int n = 0; n < 4; ++n) {
                float d2 = xv - 2.f * acc[m][n][i] + w2v[n];
                out[(size_t)row * Ndim + col0 + n * 16] = sqrtf(fmaxf(d2, 0.f));
            }
        }
    }
}

// ---------------- fallback: direct fp32, no workspace ----------------
__global__ __launch_bounds__(256) void fallback_dist_kernel(
    const float* __restrict__ x, const float* __restrict__ w, float* __restrict__ out)
{
    __shared__ float xs[16][65];   // [k][m]
    __shared__ float wsd[16][65];  // [k][n]
    const int tid = threadIdx.x;
    const int m0 = blockIdx.y * 64;
    const int n0 = blockIdx.x * 64;
    const int tx = tid & 15, ty = tid >> 4;
    float acc[4][4] = {};
    for (int k0 = 0; k0 < Kdim; k0 += 16) {
        __syncthreads();
#pragma unroll
        for (int p = 0; p < 4; ++p) {
            int idx = p * 256 + tid;  // 0..1023
            int kk = idx >> 6, c = idx & 63;
            xs[kk][c] = x[(size_t)(m0 + c) * Kdim + k0 + kk];
            wsd[kk][c] = w[(size_t)(k0 + kk) * Ndim + n0 + c];
        }
        __syncthreads();
#pragma unroll
        for (int kk = 0; kk < 16; ++kk) {
            float a[4], b[4];
#pragma unroll
            for (int i = 0; i < 4; ++i) a[i] = xs[kk][ty * 4 + i];
#pragma unroll
            for (int j = 0; j < 4; ++j) b[j] = wsd[kk][tx * 4 + j];
#pragma unroll
            for (int i = 0; i < 4; ++i)
#pragma unroll
                for (int j = 0; j < 4; ++j) {
                    float d = a[i] - b[j];
                    acc[i][j] += d * d;
                }
        }
    }
#pragma unroll
    for (int i = 0; i < 4; ++i)
#pragma unroll
        for (int j = 0; j < 4; ++j)
            out[(size_t)(m0 + ty * 4 + i) * Ndim + n0 + tx * 4 + j] = sqrtf(acc[i][j]);
}

extern "C" void kernel_launch(void* const* d_in, const int* in_sizes, int n_in,
                              void* d_out, int out_size, void* d_ws, size_t ws_size,
                              hipStream_t stream) {
    const float* x = (const float*)d_in[0];
    const float* w = (const float*)d_in[1];  // [1][4096][2048] -> [K][N]
    float* out = (float*)d_out;
    char* ws = (char*)d_ws;

    const size_t xb_bytes = (size_t)Mdim * Kdim * 2;           // 64 MB
    const size_t wb_bytes = (size_t)Ndim * Kdim * 2;           // 16 MB
    const size_t need = xb_bytes + wb_bytes + (Mdim + Ndim) * sizeof(float);

    if (ws_size >= need) {
        unsigned short* Xb = (unsigned short*)(ws);
        unsigned short* Wb = (unsigned short*)(ws + xb_bytes);
        float* x2 = (float*)(ws + xb_bytes + wb_bytes);
        float* w2 = x2 + Mdim;

        hipMemsetAsync(w2, 0, Ndim * sizeof(float), stream);
        prep_x_kernel<<<Mdim, 256, 0, stream>>>(x, Xb, x2);
        prep_wt_kernel<<<dim3(Ndim / 64, Kdim / 64), 256, 0, stream>>>(w, Wb, w2);
        const int nwg = (Mdim / TILE_M) * (Ndim / TILE_N);  // 1024
        gemm_dist_kernel<<<nwg, 256, 0, stream>>>(Xb, Wb, x2, w2, out);
    } else {
        fallback_dist_kernel<<<dim3(Ndim / 64, Mdim / 64), 256, 0, stream>>>(x, w, out);
    }
}

// Round 7
// 348.834 us; speedup vs baseline: 1.1236x; 1.1236x over previous
//
#include <hip/hip_runtime.h>

// Distances: out[b,o] = sqrt(max(|x_b|^2 - 2*x.wcol_o + |w_o|^2, 0))
// x: [8192][4096] fp32, weight: [1][4096][2048] fp32, out: [8192][2048] fp32.
// GEMM: 256x256 tile, BK=32, 4-slot LDS ring (3 tiles in flight), counted
// vmcnt(8), one asm s_barrier/iter (memory-clobber = motion fence, audit r5),
// pre-barrier lgkmcnt(0) (audit r4), setprio around MFMA cluster (T3+T4+T5),
// conflict-free chunk swizzle (rule #21 both-sides; bank algebra re-verified
// r6: each 8-lane group tiles all 32 banks, zero excess conflict).

static constexpr int Mdim = 8192;
static constexpr int Ndim = 2048;
static constexpr int Kdim = 4096;

#define BM 256
#define BN 256
#define BK 32
#define NSLOT 4

typedef float f32x4 __attribute__((ext_vector_type(4)));
typedef short s16x8 __attribute__((ext_vector_type(8)));
typedef __attribute__((address_space(3))) unsigned int lds_u32;
typedef const __attribute__((address_space(1))) unsigned int glb_u32;

__device__ __forceinline__ unsigned short f2bf(float f) {
    unsigned int u = __float_as_uint(f);
    return (unsigned short)((u + 0x7fffu + ((u >> 16) & 1u)) >> 16);  // RNE
}

// ---------------- prep: x -> bf16, x2 row norms ----------------
__global__ void prep_x_kernel(const float* __restrict__ x,
                              unsigned short* __restrict__ xb,
                              float* __restrict__ x2) {
    const int row = blockIdx.x;
    const int tid = threadIdx.x;
    const float4* xr = (const float4*)(x + (size_t)row * Kdim);
    ushort4* xo = (ushort4*)(xb + (size_t)row * Kdim);
    float ss = 0.f;
#pragma unroll
    for (int j = 0; j < 4; ++j) {
        float4 v = xr[j * 256 + tid];
        ss += v.x * v.x + v.y * v.y + v.z * v.z + v.w * v.w;
        ushort4 o;
        o.x = f2bf(v.x); o.y = f2bf(v.y); o.z = f2bf(v.z); o.w = f2bf(v.w);
        xo[j * 256 + tid] = o;
    }
#pragma unroll
    for (int d = 32; d >= 1; d >>= 1) ss += __shfl_down(ss, d, 64);
    __shared__ float ps[4];
    if ((tid & 63) == 0) ps[tid >> 6] = ss;
    __syncthreads();
    if (tid == 0) x2[row] = ps[0] + ps[1] + ps[2] + ps[3];
}

// ------- prep: w [K][N] -> wT bf16 [N][K], fused w2 column norms -------
__global__ void prep_wt_kernel(const float* __restrict__ w,
                               unsigned short* __restrict__ wb,
                               float* __restrict__ w2) {
    __shared__ float t[64][65];  // +1 pad: 2-way banks only (free)
    const int tid = threadIdx.x;
    const int c0 = blockIdx.x * 64;  // N
    const int r0 = blockIdx.y * 64;  // K
#pragma unroll
    for (int p = 0; p < 4; ++p) {
        const int r = p * 16 + (tid >> 4);
        const int c = (tid & 15) * 4;
        float4 v = *(const float4*)(w + (size_t)(r0 + r) * Ndim + c0 + c);
        t[r][c] = v.x; t[r][c + 1] = v.y; t[r][c + 2] = v.z; t[r][c + 3] = v.w;
    }
    __syncthreads();
#pragma unroll
    for (int p = 0; p < 2; ++p) {
        const int o  = p * 32 + (tid >> 3);   // output row (w column)
        const int kc = (tid & 7) * 8;         // k chunk
        float ss = 0.f;
        ushort4 a, b;
        float v;
        v = t[kc + 0][o]; ss += v * v; a.x = f2bf(v);
        v = t[kc + 1][o]; ss += v * v; a.y = f2bf(v);
        v = t[kc + 2][o]; ss += v * v; a.z = f2bf(v);
        v = t[kc + 3][o]; ss += v * v; a.w = f2bf(v);
        v = t[kc + 4][o]; ss += v * v; b.x = f2bf(v);
        v = t[kc + 5][o]; ss += v * v; b.y = f2bf(v);
        v = t[kc + 6][o]; ss += v * v; b.z = f2bf(v);
        v = t[kc + 7][o]; ss += v * v; b.w = f2bf(v);
        ushort4* dst = (ushort4*)(wb + (size_t)(c0 + o) * Kdim + r0 + kc);
        dst[0] = a; dst[1] = b;
        ss += __shfl_xor(ss, 1, 64);
        ss += __shfl_xor(ss, 2, 64);
        ss += __shfl_xor(ss, 4, 64);
        if ((tid & 7) == 0) atomicAdd(&w2[c0 + o], ss);
    }
}

// ---------------- main GEMM + fused distance epilogue ----------------
// 8 waves (2m x 4n), per-wave 128x64 out = 8x4 frags of 16x16x32 bf16.
// LDS: 4 slots x (A[256][32] | B[256][32]) bf16 = 128 KB. Slot LDS row =
// 128 B packing rows (r, r+128); 16B-chunk slot = ((r>>7)*4+cir) ^ (r&7)
// (bijective, each 8-lane group tiles all 32 banks on ds_read_b128).
__global__ __launch_bounds__(512, 2) void gemm_dist_kernel(
    const unsigned short* __restrict__ Xb,   // [M][K] bf16
    const unsigned short* __restrict__ Wb,   // [N][K] bf16
    const float* __restrict__ x2,            // [M]
    const float* __restrict__ w2,            // [N]
    float* __restrict__ out)                 // [M][N]
{
    __shared__ __align__(16) unsigned char lds[NSLOT][32768];
    const int tid = threadIdx.x;
    const int lane = tid & 63;
    const int wid = tid >> 6;
    const int wr = wid >> 2;      // m-half 0..1
    const int wcn = wid & 3;      // n-quarter 0..3

    // XCD-aware bijective swizzle: nwg = 256, q = 32
    const int nt_n = Ndim / BN;                  // 8
    const int nwg = (Mdim / BM) * nt_n;          // 256
    const int q = nwg >> 3;
    const int swz = ((int)blockIdx.x & 7) * q + ((int)blockIdx.x >> 3);
    const int bm0 = (swz / nt_n) * BM;
    const int bn0 = (swz % nt_n) * BN;

    // staging sources: chunk c (16B units) -> LDS byte c*16 = lr*128+sc*16;
    // holds global row r = lr + 128*(us>>2), k-chunk cir = us&3, us = sc^(lr&7)
    int srcA[2], srcB[2];
#pragma unroll
    for (int j = 0; j < 2; ++j) {
        int c = wid * 128 + j * 64 + lane;
        int lr = c >> 3, sc = c & 7;
        int us = sc ^ (lr & 7);
        int r = lr + ((us >> 2) << 7);
        int cir = us & 3;
        srcA[j] = (bm0 + r) * Kdim + cir * 8;
        srcB[j] = (bn0 + r) * Kdim + cir * 8;
    }

    // read offsets: row r, k-chunk (lane>>4): lr = r&127, sc = ((r>>7)*4+cir)^(r&7)
    const int aconst = (lane & 15) * 128 +
                       ((((wr << 2) | (lane >> 4)) ^ (lane & 7)) << 4);
    const int bconst = 16384 + ((wcn & 1) * 64 + (lane & 15)) * 128 +
                       (((((wcn >> 1) << 2) | (lane >> 4)) ^ (lane & 7)) << 4);

    f32x4 acc[8][4];
#pragma unroll
    for (int mi = 0; mi < 8; ++mi)
#pragma unroll
        for (int ni = 0; ni < 4; ++ni) acc[mi][ni] = (f32x4){0.f, 0.f, 0.f, 0.f};

    auto stage_tile = [&](int tt) {
        unsigned char* sb = &lds[0][0] + (tt & 3) * 32768;
        const int ko = tt * BK;
#pragma unroll
        for (int j = 0; j < 2; ++j) {
            __builtin_amdgcn_global_load_lds((glb_u32*)(Xb + srcA[j] + ko),
                (lds_u32*)(sb + wid * 2048 + j * 1024), 16, 0, 0);
            __builtin_amdgcn_global_load_lds((glb_u32*)(Wb + srcB[j] + ko),
                (lds_u32*)(sb + 16384 + wid * 2048 + j * 1024), 16, 0, 0);
        }
    };

    auto compute_slot = [&](int s) {
        const unsigned char* sb = &lds[0][0] + s * 32768;
        s16x8 a[8], b[4];
#pragma unroll
        for (int mi = 0; mi < 8; ++mi) a[mi] = *(const s16x8*)(sb + aconst + mi * 2048);
#pragma unroll
        for (int ni = 0; ni < 4; ++ni) b[ni] = *(const s16x8*)(sb + bconst + ni * 2048);
        __builtin_amdgcn_s_setprio(1);
#pragma unroll
        for (int mi = 0; mi < 8; ++mi)
#pragma unroll
            for (int ni = 0; ni < 4; ++ni)
                acc[mi][ni] = __builtin_amdgcn_mfma_f32_16x16x32_bf16(a[mi], b[ni], acc[mi][ni], 0, 0, 0);
        __builtin_amdgcn_s_setprio(0);
    };

    // prologue: 3 tiles in flight (12 loads/wave)
    stage_tile(0); stage_tile(1); stage_tile(2);

    const int NT = Kdim / BK;  // 128
    // Main loop. Pre-barrier wait: vmcnt(8) = own tile-t loads landed;
    // lgkmcnt(0) = own slot reads from iter t-1 in registers. Barrier is
    // asm volatile + "memory": no ds_read/DMA may be compiler-moved across
    // it, so cross-wave tile-t visibility holds (audit r5).
    for (int t = 0; t < NT - 3; ++t) {
        asm volatile("s_waitcnt vmcnt(8) lgkmcnt(0)" ::: "memory");
        asm volatile("s_barrier" ::: "memory");
        stage_tile(t + 3);
        compute_slot(t & 3);
    }
    asm volatile("s_waitcnt vmcnt(8) lgkmcnt(0)" ::: "memory");   // drain tile NT-3
    asm volatile("s_barrier" ::: "memory");
    compute_slot((NT - 3) & 3);
    asm volatile("s_waitcnt vmcnt(4) lgkmcnt(0)" ::: "memory");   // drain tile NT-2
    asm volatile("s_barrier" ::: "memory");
    compute_slot((NT - 2) & 3);
    asm volatile("s_waitcnt vmcnt(0) lgkmcnt(0)" ::: "memory");   // drain tile NT-1
    asm volatile("s_barrier" ::: "memory");
    compute_slot((NT - 1) & 3);

    // epilogue: D mapping col=lane&15, row=(lane>>4)*4+reg [m89/m91-verified]
    const int col0 = bn0 + wcn * 64 + (lane & 15);
    const int rb0 = bm0 + wr * 128 + ((lane >> 4) << 2);
    float w2v[4];
#pragma unroll
    for (int ni = 0; ni < 4; ++ni) w2v[ni] = w2[col0 + ni * 16];
#pragma unroll
    for (int mi = 0; mi < 8; ++mi) {
#pragma unroll
        for (int i = 0; i < 4; ++i) {
            const int row = rb0 + mi * 16 + i;
            const float xv = x2[row];
#pragma unroll
            for (int ni = 0; ni < 4; ++ni) {
                float d2 = xv - 2.f * acc[mi][ni][i] + w2v[ni];
                out[(size_t)row * Ndim + col0 + ni * 16] = sqrtf(fmaxf(d2, 0.f));
            }
        }
    }
}

// ---------------- fallback: direct fp32, no workspace ----------------
__global__ __launch_bounds__(256) void fallback_dist_kernel(
    const float* __restrict__ x, const float* __restrict__ w, float* __restrict__ out)
{
    __shared__ float xs[16][65];
    __shared__ float wsd[16][65];
    const int tid = threadIdx.x;
    const int m0 = blockIdx.y * 64;
    const int n0 = blockIdx.x * 64;
    const int tx = tid & 15, ty = tid >> 4;
    float acc[4][4] = {};
    for (int k0 = 0; k0 < Kdim; k0 += 16) {
        __syncthreads();
#pragma unroll
        for (int p = 0; p < 4; ++p) {
            int idx = p * 256 + tid;
            int kk = idx >> 6, c = idx & 63;
            xs[kk][c] = x[(size_t)(m0 + c) * Kdim + k0 + kk];
            wsd[kk][c] = w[(size_t)(k0 + kk) * Ndim + n0 + c];
        }
        __syncthreads();
#pragma unroll
        for (int kk = 0; kk < 16; ++kk) {
            float a[4], b[4];
#pragma unroll
            for (int i = 0; i < 4; ++i) a[i] = xs[kk][ty * 4 + i];
#pragma unroll
            for (int j = 0; j < 4; ++j) b[j] = wsd[kk][tx * 4 + j];
#pragma unroll
            for (int i = 0; i < 4; ++i)
#pragma unroll
                for (int j = 0; j < 4; ++j) {
                    float d = a[i] - b[j];
                    acc[i][j] += d * d;
                }
        }
    }
#pragma unroll
    for (int i = 0; i < 4; ++i)
#pragma unroll
        for (int j = 0; j < 4; ++j)
            out[(size_t)(m0 + ty * 4 + i) * Ndim + n0 + tx * 4 + j] = sqrtf(acc[i][j]);
}

extern "C" void kernel_launch(void* const* d_in, const int* in_sizes, int n_in,
                              void* d_out, int out_size, void* d_ws, size_t ws_size,
                              hipStream_t stream) {
    const float* x = (const float*)d_in[0];
    const float* w = (const float*)d_in[1];  // [1][4096][2048] -> [K][N]
    float* out = (float*)d_out;
    char* ws = (char*)d_ws;

    const size_t xb_bytes = (size_t)Mdim * Kdim * 2;           // 64 MB
    const size_t wb_bytes = (size_t)Ndim * Kdim * 2;           // 16 MB
    const size_t need = xb_bytes + wb_bytes + (Mdim + Ndim) * sizeof(float);

    if (ws_size >= need) {
        unsigned short* Xb = (unsigned short*)(ws);
        unsigned short* Wb = (unsigned short*)(ws + xb_bytes);
        float* x2 = (float*)(ws + xb_bytes + wb_bytes);
        float* w2 = x2 + Mdim;

        hipMemsetAsync(w2, 0, Ndim * sizeof(float), stream);
        prep_x_kernel<<<Mdim, 256, 0, stream>>>(x, Xb, x2);
        prep_wt_kernel<<<dim3(Ndim / 64, Kdim / 64), 256, 0, stream>>>(w, Wb, w2);
        const int nwg = (Mdim / BM) * (Ndim / BN);  // 256
        gemm_dist_kernel<<<nwg, 512, 0, stream>>>(Xb, Wb, x2, w2, out);
    } else {
        fallback_dist_kernel<<<dim3(Ndim / 64, Mdim / 64), 256, 0, stream>>>(x, w, out);
    }
}